// Round 1
// baseline (2079.534 us; speedup 1.0000x reference)
//
#include <hip/hip_runtime.h>
#include <hip/hip_bf16.h>
#include <math.h>

// Problem constants
#define Bn   32
#define Hh   56
#define Wd   56
#define Cc   192
#define NHh  6
#define HDim 32
#define HIDN 768
#define Tt   (Bn*Hh*Wd)          // 100352 tokens
#define NWIN (Bn*64)             // 2048 windows
#define TOTQ (Tt*Cc)             // elems per q/k/v buffer (19267584)

typedef __attribute__((ext_vector_type(8))) short short8;
typedef __attribute__((ext_vector_type(4))) float floatx4;

__device__ __forceinline__ short f2bf(float f) {
    unsigned u = __float_as_uint(f);
    u += 0x7fffu + ((u >> 16) & 1u);     // round-to-nearest-even
    return (short)(u >> 16);
}
__device__ __forceinline__ float bf2f(short s) {
    return __uint_as_float(((unsigned)(unsigned short)s) << 16);
}

// ---------------------------------------------------------------------------
// Weight transpose + bf16 convert: W[K,N] fp32 -> WT[N,K] bf16
// ---------------------------------------------------------------------------
__global__ void k_transpose(const float* __restrict__ W, short* __restrict__ WT,
                            int K, int N) {
    int idx = blockIdx.x * 256 + threadIdx.x;
    if (idx >= K * N) return;
    int n = idx / K, k = idx % K;        // coalesced writes
    WT[idx] = f2bf(W[k * N + n]);
}

// ---------------------------------------------------------------------------
// Fused depthwise-3x3 CPE (residual) + LayerNorm.
// One block (192 threads) per token. Writes:
//   ysum_out fp32 token-major  = x + conv(x) + bconv      (residual carrier)
//   ln_out   bf16              = LN(ysum)*g+b   (windowed or token-major rows)
// ---------------------------------------------------------------------------
__global__ void __launch_bounds__(192) k_cpe_ln(
    const float* __restrict__ xin, const float* __restrict__ wconv,
    const float* __restrict__ bconv, const float* __restrict__ g,
    const float* __restrict__ beta, float* __restrict__ ysum_out,
    short* __restrict__ ln_out, int windowed)
{
    int blk = blockIdx.x;
    int b = blk / (Hh * Wd);
    int rem = blk % (Hh * Wd);
    int h = rem / Wd, w = rem % Wd;
    int c = threadIdx.x;

    __shared__ float wl[Cc * 9];
    __shared__ float red[6];
    for (int i = c; i < Cc * 9; i += 192) wl[i] = wconv[i];
    __syncthreads();

    float s = bconv[c];
    #pragma unroll
    for (int ky = 0; ky < 3; ++ky) {
        int hy = h + ky - 1;
        if (hy < 0 || hy >= Hh) continue;
        #pragma unroll
        for (int kx = 0; kx < 3; ++kx) {
            int wx = w + kx - 1;
            if (wx < 0 || wx >= Wd) continue;
            s += wl[c * 9 + ky * 3 + kx] *
                 xin[((size_t)b * (Hh * Wd) + hy * Wd + wx) * Cc + c];
        }
    }
    float val = xin[(size_t)blk * Cc + c] + s;
    ysum_out[(size_t)blk * Cc + c] = val;

    // block LN reduction (3 waves)
    float p = val, p2 = val * val;
    #pragma unroll
    for (int off = 32; off; off >>= 1) {
        p  += __shfl_xor(p,  off, 64);
        p2 += __shfl_xor(p2, off, 64);
    }
    int wid = c >> 6;
    if ((c & 63) == 0) { red[wid * 2] = p; red[wid * 2 + 1] = p2; }
    __syncthreads();
    float sum  = red[0] + red[2] + red[4];
    float sum2 = red[1] + red[3] + red[5];
    float mean = sum * (1.0f / Cc);
    float var  = sum2 * (1.0f / Cc) - mean * mean;
    float nrm  = (val - mean) * rsqrtf(var + 1e-5f) * g[c] + beta[c];

    int r;
    if (windowed) {
        // dilated window mapping: h = w_h*8 + nw_h
        int win = b * 64 + (h & 7) * 8 + (w & 7);
        int pos = (h >> 3) * 7 + (w >> 3);
        r = win * 49 + pos;
    } else {
        r = blk;
    }
    ln_out[(size_t)r * Cc + c] = f2bf(nrm);
}

// ---------------------------------------------------------------------------
// MFMA wave core: one wave computes a 16x64 output strip (4 accumulators).
// A[M,K] bf16 row-major; BT[N,K] bf16 (B transposed). Direct global loads.
// ---------------------------------------------------------------------------
__device__ __forceinline__ void gemm_wave_core(
    const short* __restrict__ A, const short* __restrict__ BT,
    int K, int m0, int n0, int lane, floatx4 acc[4])
{
    const int lrow = lane & 15;
    const int quad = lane >> 4;
    const short* aptr = A + (size_t)(m0 + lrow) * K + quad * 8;
    const short* b0 = BT + (size_t)(n0 +  0 + lrow) * K + quad * 8;
    const short* b1 = BT + (size_t)(n0 + 16 + lrow) * K + quad * 8;
    const short* b2 = BT + (size_t)(n0 + 32 + lrow) * K + quad * 8;
    const short* b3 = BT + (size_t)(n0 + 48 + lrow) * K + quad * 8;
    for (int k0 = 0; k0 < K; k0 += 32) {
        short8 a = *(const short8*)(aptr + k0);
        acc[0] = __builtin_amdgcn_mfma_f32_16x16x32_bf16(a, *(const short8*)(b0 + k0), acc[0], 0, 0, 0);
        acc[1] = __builtin_amdgcn_mfma_f32_16x16x32_bf16(a, *(const short8*)(b1 + k0), acc[1], 0, 0, 0);
        acc[2] = __builtin_amdgcn_mfma_f32_16x16x32_bf16(a, *(const short8*)(b2 + k0), acc[2], 0, 0, 0);
        acc[3] = __builtin_amdgcn_mfma_f32_16x16x32_bf16(a, *(const short8*)(b3 + k0), acc[3], 0, 0, 0);
    }
}

// QKV GEMM: A = windowed LN rows [Tt,192]; N=576; scatter into q/k/v buffers.
__global__ void __launch_bounds__(256) k_gemm_qkv(
    const short* __restrict__ A, const short* __restrict__ BT,
    const float* __restrict__ bias, short* __restrict__ qkv)
{
    int m0 = blockIdx.x * 64 + (threadIdx.x >> 6) * 16;
    int n0 = blockIdx.y * 64;
    int lane = threadIdx.x & 63;
    floatx4 acc[4] = {{0,0,0,0},{0,0,0,0},{0,0,0,0},{0,0,0,0}};
    gemm_wave_core(A, BT, Cc, m0, n0, lane, acc);
    int lrow = lane & 15, quad = lane >> 4;
    #pragma unroll
    for (int i = 0; i < 4; ++i) {
        int col = n0 + i * 16 + lrow;
        int d = col / 18, rm = col % 18;
        int k3 = rm / 6, h6 = rm % 6;      // 'b n (d k h)' split
        float bv = bias[col];
        #pragma unroll
        for (int t = 0; t < 4; ++t) {
            int r = m0 + quad * 4 + t;
            int win = r / 49, p = r % 49;
            qkv[(size_t)k3 * TOTQ + (((size_t)win * NHh + h6) * 49 + p) * HDim + d] =
                f2bf(acc[i][t] + bv);
        }
    }
}

// Attention per (window, head): QK^T, softmax, @V  (fp32 VALU in LDS)
__global__ void __launch_bounds__(256) k_attn(
    const short* __restrict__ qkv, short* __restrict__ aout)
{
    int win = blockIdx.x, h6 = blockIdx.y;
    __shared__ float Q[49 * 32], Kx[49 * 32], V[49 * 32], S[49 * 49];
    size_t base = ((size_t)win * NHh + h6) * 49 * 32;
    for (int i = threadIdx.x; i < 49 * 32; i += 256) {
        Q[i]  = bf2f(qkv[base + i]) * 0.17677669529663688f;  // 1/sqrt(32)
        Kx[i] = bf2f(qkv[(size_t)TOTQ + base + i]);
        V[i]  = bf2f(qkv[2 * (size_t)TOTQ + base + i]);
    }
    __syncthreads();
    for (int idx = threadIdx.x; idx < 49 * 49; idx += 256) {
        int i = idx / 49, j = idx % 49;
        float s = 0.f;
        #pragma unroll
        for (int d = 0; d < 32; ++d) s += Q[i * 32 + d] * Kx[j * 32 + d];
        S[idx] = s;
    }
    __syncthreads();
    if (threadIdx.x < 49) {
        int i = threadIdx.x;
        float mx = -1e30f;
        for (int j = 0; j < 49; ++j) mx = fmaxf(mx, S[i * 49 + j]);
        float sum = 0.f;
        for (int j = 0; j < 49; ++j) {
            float e = __expf(S[i * 49 + j] - mx);
            S[i * 49 + j] = e; sum += e;
        }
        float inv = 1.0f / sum;
        for (int j = 0; j < 49; ++j) S[i * 49 + j] *= inv;
    }
    __syncthreads();
    for (int idx = threadIdx.x; idx < 49 * 32; idx += 256) {
        int i = idx / 32, d = idx % 32;
        float s = 0.f;
        for (int j = 0; j < 49; ++j) s += S[i * 49 + j] * V[j * 32 + d];
        int r = win * 49 + i;
        aout[(size_t)r * Cc + h6 * HDim + d] = f2bf(s);   // 'b h n d -> b n (h d)'
    }
}

// proj GEMM: A = attn-out (windowed rows); epilogue scatters to token order,
// adds proj bias + shortcut, writes y0 in place over shortcut buffer.
__global__ void __launch_bounds__(256) k_gemm_proj(
    const short* __restrict__ A, const short* __restrict__ BT,
    const float* __restrict__ bias, float* __restrict__ y0)
{
    int m0 = blockIdx.x * 64 + (threadIdx.x >> 6) * 16;
    int n0 = blockIdx.y * 64;
    int lane = threadIdx.x & 63;
    floatx4 acc[4] = {{0,0,0,0},{0,0,0,0},{0,0,0,0},{0,0,0,0}};
    gemm_wave_core(A, BT, Cc, m0, n0, lane, acc);
    int lrow = lane & 15, quad = lane >> 4;
    #pragma unroll
    for (int i = 0; i < 4; ++i) {
        int col = n0 + i * 16 + lrow;
        float bv = bias[col];
        #pragma unroll
        for (int t = 0; t < 4; ++t) {
            int r = m0 + quad * 4 + t;
            int win = r / 49, p = r % 49;
            int b = win >> 6, wm = (win >> 3) & 7, wwm = win & 7;
            int h = (p / 7) * 8 + wm, w = (p % 7) * 8 + wwm;   // window reverse
            size_t ti = ((size_t)b * (Hh * Wd) + h * Wd + w) * Cc + col;
            y0[ti] += acc[i][t] + bv;
        }
    }
}

// fc1 GEMM + exact GELU -> h1 bf16 [Tt, 768]
__global__ void __launch_bounds__(256) k_gemm_fc1(
    const short* __restrict__ A, const short* __restrict__ BT,
    const float* __restrict__ bias, short* __restrict__ h1)
{
    int m0 = blockIdx.x * 64 + (threadIdx.x >> 6) * 16;
    int n0 = blockIdx.y * 64;
    int lane = threadIdx.x & 63;
    floatx4 acc[4] = {{0,0,0,0},{0,0,0,0},{0,0,0,0},{0,0,0,0}};
    gemm_wave_core(A, BT, Cc, m0, n0, lane, acc);
    int lrow = lane & 15, quad = lane >> 4;
    #pragma unroll
    for (int i = 0; i < 4; ++i) {
        int col = n0 + i * 16 + lrow;
        float bv = bias[col];
        #pragma unroll
        for (int t = 0; t < 4; ++t) {
            int r = m0 + quad * 4 + t;
            float v = acc[i][t] + bv;
            float gl = 0.5f * v * (1.0f + erff(v * 0.70710678118654752f));
            h1[(size_t)r * HIDN + col] = f2bf(gl);
        }
    }
}

// fc2 GEMM (K=768) + bias + residual add into d_out (holds y)
__global__ void __launch_bounds__(256) k_gemm_fc2(
    const short* __restrict__ A, const short* __restrict__ BT,
    const float* __restrict__ bias, float* __restrict__ out)
{
    int m0 = blockIdx.x * 64 + (threadIdx.x >> 6) * 16;
    int n0 = blockIdx.y * 64;
    int lane = threadIdx.x & 63;
    floatx4 acc[4] = {{0,0,0,0},{0,0,0,0},{0,0,0,0},{0,0,0,0}};
    gemm_wave_core(A, BT, HIDN, m0, n0, lane, acc);
    int lrow = lane & 15, quad = lane >> 4;
    #pragma unroll
    for (int i = 0; i < 4; ++i) {
        int col = n0 + i * 16 + lrow;
        float bv = bias[col];
        #pragma unroll
        for (int t = 0; t < 4; ++t) {
            int r = m0 + quad * 4 + t;
            size_t idx = (size_t)r * Cc + col;
            out[idx] += acc[i][t] + bv;
        }
    }
}

// ---------------------------------------------------------------------------
extern "C" void kernel_launch(void* const* d_in, const int* in_sizes, int n_in,
                              void* d_out, int out_size, void* d_ws, size_t ws_size,
                              hipStream_t stream)
{
    (void)in_sizes; (void)n_in; (void)out_size; (void)ws_size;
    const float* x      = (const float*)d_in[0];
    const float* cpe0_w = (const float*)d_in[3];
    const float* cpe0_b = (const float*)d_in[4];
    const float* cpe1_w = (const float*)d_in[5];
    const float* cpe1_b = (const float*)d_in[6];
    const float* n1_g   = (const float*)d_in[7];
    const float* n1_b   = (const float*)d_in[8];
    const float* qkv_w  = (const float*)d_in[9];
    const float* qkv_b  = (const float*)d_in[10];
    const float* proj_w = (const float*)d_in[11];
    const float* proj_b = (const float*)d_in[12];
    const float* n2_g   = (const float*)d_in[13];
    const float* n2_b   = (const float*)d_in[14];
    const float* fc1_w  = (const float*)d_in[15];
    const float* fc1_b  = (const float*)d_in[16];
    const float* fc2_w  = (const float*)d_in[17];
    const float* fc2_b  = (const float*)d_in[18];
    float* out = (float*)d_out;

    // workspace layout (bytes); total 270,630,912
    char* ws = (char*)d_ws;
    float* shortcut = (float*)ws;                     // 77,070,336  (fp32 Tt*192)
    short* lnbuf    = (short*)(ws + 77070336);        // 38,535,168  (bf16 Tt*192)
    short* qkvbuf   = (short*)(ws + 115605504);       // 115,605,504 (3x bf16)
    short* attnout  = (short*)(ws + 231211008);       // 38,535,168
    short* h1       = qkvbuf;                         // overlays qkv+attn (154,140,672)
    short* wqkvT    = (short*)(ws + 269746176);       // 221,184
    short* wprojT   = (short*)(ws + 269967360);       // 73,728
    short* wfc1T    = (short*)(ws + 270041088);       // 294,912
    short* wfc2T    = (short*)(ws + 270336000);       // 294,912

    // weight converts/transposes
    k_transpose<<<dim3((192 * 576 + 255) / 256), dim3(256), 0, stream>>>(qkv_w, wqkvT, 192, 576);
    k_transpose<<<dim3((192 * 192 + 255) / 256), dim3(256), 0, stream>>>(proj_w, wprojT, 192, 192);
    k_transpose<<<dim3((192 * 768 + 255) / 256), dim3(256), 0, stream>>>(fc1_w, wfc1T, 192, 768);
    k_transpose<<<dim3((768 * 192 + 255) / 256), dim3(256), 0, stream>>>(fc2_w, wfc2T, 768, 192);

    // stage 1: cpe0 + LN1 (windowed bf16 ln out)
    k_cpe_ln<<<dim3(Tt), dim3(192), 0, stream>>>(x, cpe0_w, cpe0_b, n1_g, n1_b,
                                                 shortcut, lnbuf, 1);
    // qkv projection
    k_gemm_qkv<<<dim3(Tt / 64, 9), dim3(256), 0, stream>>>(lnbuf, wqkvT, qkv_b, qkvbuf);
    // window attention
    k_attn<<<dim3(NWIN, NHh), dim3(256), 0, stream>>>(qkvbuf, attnout);
    // output projection + shortcut residual -> y0 (in place over shortcut)
    k_gemm_proj<<<dim3(Tt / 64, 3), dim3(256), 0, stream>>>(attnout, wprojT, proj_b, shortcut);
    // stage 2: cpe1 + LN2 (token-major ln out); y -> d_out
    k_cpe_ln<<<dim3(Tt), dim3(192), 0, stream>>>(shortcut, cpe1_w, cpe1_b, n2_g, n2_b,
                                                 out, lnbuf, 0);
    // MLP
    k_gemm_fc1<<<dim3(Tt / 64, 12), dim3(256), 0, stream>>>(lnbuf, wfc1T, fc1_b, h1);
    k_gemm_fc2<<<dim3(Tt / 64, 3), dim3(256), 0, stream>>>(h1, wfc2T, fc2_b, out);
}

// Round 2
// 1569.043 us; speedup vs baseline: 1.3254x; 1.3254x over previous
//
#include <hip/hip_runtime.h>
#include <hip/hip_bf16.h>
#include <math.h>

// Problem constants
#define Bn   32
#define Hh   56
#define Wd   56
#define Cc   192
#define NHh  6
#define HDim 32
#define HIDN 768
#define Tt   (Bn*Hh*Wd)          // 100352 tokens
#define NWIN (Bn*64)             // 2048 windows

typedef __attribute__((ext_vector_type(8))) short short8;
typedef __attribute__((ext_vector_type(4))) float floatx4;

__device__ __forceinline__ short f2bf(float f) {
    unsigned u = __float_as_uint(f);
    u += 0x7fffu + ((u >> 16) & 1u);     // round-to-nearest-even
    return (short)(u >> 16);
}
__device__ __forceinline__ float bf2f(short s) {
    return __uint_as_float(((unsigned)(unsigned short)s) << 16);
}

// ---------------------------------------------------------------------------
// Weight transpose + bf16 convert: W[K,N] fp32 -> WT[N,K] bf16
// ---------------------------------------------------------------------------
__global__ void k_transpose(const float* __restrict__ W, short* __restrict__ WT,
                            int K, int N) {
    int idx = blockIdx.x * 256 + threadIdx.x;
    if (idx >= K * N) return;
    int n = idx / K, k = idx % K;        // coalesced writes
    WT[idx] = f2bf(W[k * N + n]);
}

// ---------------------------------------------------------------------------
// Fused depthwise-3x3 CPE (residual) + LayerNorm. 8 tokens per block.
//   ysum_out fp32 token-major  = x + conv(x) + bconv      (residual carrier)
//   ln_out   bf16              = LN(ysum)*g+b   (windowed or token-major rows)
// ---------------------------------------------------------------------------
#define CPE_TPB 8
__global__ void __launch_bounds__(192) k_cpe_ln(
    const float* __restrict__ xin, const float* __restrict__ wconv,
    const float* __restrict__ bconv, const float* __restrict__ g,
    const float* __restrict__ beta, float* __restrict__ ysum_out,
    short* __restrict__ ln_out, int windowed)
{
    int c = threadIdx.x;
    __shared__ float wl[Cc * 9];
    __shared__ float red[6];
    for (int i = c; i < Cc * 9; i += 192) wl[i] = wconv[i];
    float bcv = bconv[c], gc = g[c], bc = beta[c];
    __syncthreads();

    int t0 = blockIdx.x * CPE_TPB;
    for (int tk = 0; tk < CPE_TPB; ++tk) {
        int blk = t0 + tk;
        int b = blk / (Hh * Wd);
        int rem = blk % (Hh * Wd);
        int h = rem / Wd, w = rem % Wd;

        float s = bcv;
        #pragma unroll
        for (int ky = 0; ky < 3; ++ky) {
            int hy = h + ky - 1;
            if (hy < 0 || hy >= Hh) continue;
            #pragma unroll
            for (int kx = 0; kx < 3; ++kx) {
                int wx = w + kx - 1;
                if (wx < 0 || wx >= Wd) continue;
                s += wl[c * 9 + ky * 3 + kx] *
                     xin[((size_t)b * (Hh * Wd) + hy * Wd + wx) * Cc + c];
            }
        }
        float val = xin[(size_t)blk * Cc + c] + s;
        ysum_out[(size_t)blk * Cc + c] = val;

        float p = val, p2 = val * val;
        #pragma unroll
        for (int off = 32; off; off >>= 1) {
            p  += __shfl_xor(p,  off, 64);
            p2 += __shfl_xor(p2, off, 64);
        }
        int wid = c >> 6;
        if ((c & 63) == 0) { red[wid * 2] = p; red[wid * 2 + 1] = p2; }
        __syncthreads();
        float sum  = red[0] + red[2] + red[4];
        float sum2 = red[1] + red[3] + red[5];
        __syncthreads();   // red consumed; safe to overwrite next iter
        float mean = sum * (1.0f / Cc);
        float var  = sum2 * (1.0f / Cc) - mean * mean;
        float nrm  = (val - mean) * rsqrtf(var + 1e-5f) * gc + bc;

        int r;
        if (windowed) {
            // dilated window mapping: h = w_h*8 + nw_h
            int win = b * 64 + (h & 7) * 8 + (w & 7);
            int pos = (h >> 3) * 7 + (w >> 3);
            r = win * 49 + pos;
        } else {
            r = blk;
        }
        ln_out[(size_t)r * Cc + c] = f2bf(nrm);
    }
}

// ---------------------------------------------------------------------------
// MFMA wave core: one wave computes a 16x64 output strip (4 accumulators).
// A[M,K] bf16 row-major; BT[N,K] bf16 (B transposed). Direct global loads.
// ---------------------------------------------------------------------------
__device__ __forceinline__ void gemm_wave_core(
    const short* __restrict__ A, const short* __restrict__ BT,
    int K, int m0, int n0, int lane, floatx4 acc[4])
{
    const int lrow = lane & 15;
    const int quad = lane >> 4;
    const short* aptr = A + (size_t)(m0 + lrow) * K + quad * 8;
    const short* b0 = BT + (size_t)(n0 +  0 + lrow) * K + quad * 8;
    const short* b1 = BT + (size_t)(n0 + 16 + lrow) * K + quad * 8;
    const short* b2 = BT + (size_t)(n0 + 32 + lrow) * K + quad * 8;
    const short* b3 = BT + (size_t)(n0 + 48 + lrow) * K + quad * 8;
    for (int k0 = 0; k0 < K; k0 += 32) {
        short8 a = *(const short8*)(aptr + k0);
        acc[0] = __builtin_amdgcn_mfma_f32_16x16x32_bf16(a, *(const short8*)(b0 + k0), acc[0], 0, 0, 0);
        acc[1] = __builtin_amdgcn_mfma_f32_16x16x32_bf16(a, *(const short8*)(b1 + k0), acc[1], 0, 0, 0);
        acc[2] = __builtin_amdgcn_mfma_f32_16x16x32_bf16(a, *(const short8*)(b2 + k0), acc[2], 0, 0, 0);
        acc[3] = __builtin_amdgcn_mfma_f32_16x16x32_bf16(a, *(const short8*)(b3 + k0), acc[3], 0, 0, 0);
    }
}

// QKV GEMM: natural row-major bf16 output [Tt, 576] (+bias). Coalesced stores.
__global__ void __launch_bounds__(256) k_gemm_qkv(
    const short* __restrict__ A, const short* __restrict__ BT,
    const float* __restrict__ bias, short* __restrict__ qkv)
{
    int n0 = blockIdx.x * 64;
    int m0 = blockIdx.y * 64 + (threadIdx.x >> 6) * 16;
    int lane = threadIdx.x & 63;
    floatx4 acc[4] = {{0,0,0,0},{0,0,0,0},{0,0,0,0},{0,0,0,0}};
    gemm_wave_core(A, BT, Cc, m0, n0, lane, acc);
    int lrow = lane & 15, quad = lane >> 4;
    #pragma unroll
    for (int i = 0; i < 4; ++i) {
        int col = n0 + i * 16 + lrow;
        float bv = bias[col];
        #pragma unroll
        for (int t = 0; t < 4; ++t) {
            int r = m0 + quad * 4 + t;
            qkv[(size_t)r * 576 + col] = f2bf(acc[i][t] + bv);
        }
    }
}

// ---------------------------------------------------------------------------
// Window attention: one block per window, 6 heads sequential.
// Gathers Q/K/V from natural qkv layout: col = d*18 + k3*6 + h6.
// ---------------------------------------------------------------------------
__global__ void __launch_bounds__(256) k_attn(
    const short* __restrict__ C, short* __restrict__ aout)
{
    int win = blockIdx.x;
    __shared__ float Qf[49 * 33], Kf[49 * 33], Vf[49 * 33];
    __shared__ float S[49 * 49];
    size_t rbase = (size_t)win * 49 * 576;
    for (int h6 = 0; h6 < NHh; ++h6) {
        for (int idx = threadIdx.x; idx < 49 * 32; idx += 256) {
            int p = idx >> 5, d = idx & 31;
            size_t ro = rbase + (size_t)p * 576 + d * 18 + h6;
            Qf[p * 33 + d] = bf2f(C[ro]) * 0.17677669529663688f;   // 1/sqrt(32)
            Kf[p * 33 + d] = bf2f(C[ro + 6]);
            Vf[p * 33 + d] = bf2f(C[ro + 12]);
        }
        __syncthreads();
        for (int idx = threadIdx.x; idx < 49 * 49; idx += 256) {
            int i = idx / 49, j = idx % 49;
            float s = 0.f;
            #pragma unroll
            for (int d = 0; d < 32; ++d) s += Qf[i * 33 + d] * Kf[j * 33 + d];
            S[idx] = s;
        }
        __syncthreads();
        if (threadIdx.x < 49) {
            int i = threadIdx.x;
            float mx = -1e30f;
            for (int j = 0; j < 49; ++j) mx = fmaxf(mx, S[i * 49 + j]);
            float sum = 0.f;
            for (int j = 0; j < 49; ++j) {
                float e = __expf(S[i * 49 + j] - mx);
                S[i * 49 + j] = e; sum += e;
            }
            float inv = 1.0f / sum;
            for (int j = 0; j < 49; ++j) S[i * 49 + j] *= inv;
        }
        __syncthreads();
        for (int idx = threadIdx.x; idx < 49 * 32; idx += 256) {
            int p = idx >> 5, d = idx & 31;
            float s = 0.f;
            #pragma unroll
            for (int j = 0; j < 49; ++j) s += S[p * 49 + j] * Vf[j * 33 + d];
            aout[((size_t)win * 49 + p) * Cc + h6 * HDim + d] = f2bf(s);
        }
        __syncthreads();
    }
}

// proj GEMM: A = attn-out (windowed rows); epilogue scatters to token order,
// adds proj bias + shortcut, writes y0 in place over shortcut buffer.
__global__ void __launch_bounds__(256) k_gemm_proj(
    const short* __restrict__ A, const short* __restrict__ BT,
    const float* __restrict__ bias, float* __restrict__ y0)
{
    int n0 = blockIdx.x * 64;
    int m0 = blockIdx.y * 64 + (threadIdx.x >> 6) * 16;
    int lane = threadIdx.x & 63;
    floatx4 acc[4] = {{0,0,0,0},{0,0,0,0},{0,0,0,0},{0,0,0,0}};
    gemm_wave_core(A, BT, Cc, m0, n0, lane, acc);
    int lrow = lane & 15, quad = lane >> 4;
    #pragma unroll
    for (int i = 0; i < 4; ++i) {
        int col = n0 + i * 16 + lrow;
        float bv = bias[col];
        #pragma unroll
        for (int t = 0; t < 4; ++t) {
            int r = m0 + quad * 4 + t;
            int win = r / 49, p = r % 49;
            int b = win >> 6, wm = (win >> 3) & 7, wwm = win & 7;
            int h = (p / 7) * 8 + wm, w = (p % 7) * 8 + wwm;   // window reverse
            size_t ti = ((size_t)b * (Hh * Wd) + h * Wd + w) * Cc + col;
            y0[ti] += acc[i][t] + bv;
        }
    }
}

// fc1 GEMM + exact GELU -> h1 bf16 [Tt, 768]
__global__ void __launch_bounds__(256) k_gemm_fc1(
    const short* __restrict__ A, const short* __restrict__ BT,
    const float* __restrict__ bias, short* __restrict__ h1)
{
    int n0 = blockIdx.x * 64;
    int m0 = blockIdx.y * 64 + (threadIdx.x >> 6) * 16;
    int lane = threadIdx.x & 63;
    floatx4 acc[4] = {{0,0,0,0},{0,0,0,0},{0,0,0,0},{0,0,0,0}};
    gemm_wave_core(A, BT, Cc, m0, n0, lane, acc);
    int lrow = lane & 15, quad = lane >> 4;
    #pragma unroll
    for (int i = 0; i < 4; ++i) {
        int col = n0 + i * 16 + lrow;
        float bv = bias[col];
        #pragma unroll
        for (int t = 0; t < 4; ++t) {
            int r = m0 + quad * 4 + t;
            float v = acc[i][t] + bv;
            float gl = 0.5f * v * (1.0f + erff(v * 0.70710678118654752f));
            h1[(size_t)r * HIDN + col] = f2bf(gl);
        }
    }
}

// fc2 GEMM (K=768) + bias + residual add into d_out (holds y)
__global__ void __launch_bounds__(256) k_gemm_fc2(
    const short* __restrict__ A, const short* __restrict__ BT,
    const float* __restrict__ bias, float* __restrict__ out)
{
    int n0 = blockIdx.x * 64;
    int m0 = blockIdx.y * 64 + (threadIdx.x >> 6) * 16;
    int lane = threadIdx.x & 63;
    floatx4 acc[4] = {{0,0,0,0},{0,0,0,0},{0,0,0,0},{0,0,0,0}};
    gemm_wave_core(A, BT, HIDN, m0, n0, lane, acc);
    int lrow = lane & 15, quad = lane >> 4;
    #pragma unroll
    for (int i = 0; i < 4; ++i) {
        int col = n0 + i * 16 + lrow;
        float bv = bias[col];
        #pragma unroll
        for (int t = 0; t < 4; ++t) {
            int r = m0 + quad * 4 + t;
            size_t idx = (size_t)r * Cc + col;
            out[idx] += acc[i][t] + bv;
        }
    }
}

// ---------------------------------------------------------------------------
extern "C" void kernel_launch(void* const* d_in, const int* in_sizes, int n_in,
                              void* d_out, int out_size, void* d_ws, size_t ws_size,
                              hipStream_t stream)
{
    (void)in_sizes; (void)n_in; (void)out_size; (void)ws_size;
    const float* x      = (const float*)d_in[0];
    const float* cpe0_w = (const float*)d_in[3];
    const float* cpe0_b = (const float*)d_in[4];
    const float* cpe1_w = (const float*)d_in[5];
    const float* cpe1_b = (const float*)d_in[6];
    const float* n1_g   = (const float*)d_in[7];
    const float* n1_b   = (const float*)d_in[8];
    const float* qkv_w  = (const float*)d_in[9];
    const float* qkv_b  = (const float*)d_in[10];
    const float* proj_w = (const float*)d_in[11];
    const float* proj_b = (const float*)d_in[12];
    const float* n2_g   = (const float*)d_in[13];
    const float* n2_b   = (const float*)d_in[14];
    const float* fc1_w  = (const float*)d_in[15];
    const float* fc1_b  = (const float*)d_in[16];
    const float* fc2_w  = (const float*)d_in[17];
    const float* fc2_b  = (const float*)d_in[18];
    float* out = (float*)d_out;

    // workspace layout (bytes); total 270,630,912
    char* ws = (char*)d_ws;
    float* shortcut = (float*)ws;                     // 77,070,336  (fp32 Tt*192)
    short* lnbuf    = (short*)(ws + 77070336);        // 38,535,168  (bf16 Tt*192)
    short* qkvbuf   = (short*)(ws + 115605504);       // 115,605,504 (bf16 Tt*576)
    short* attnout  = (short*)(ws + 231211008);       // 38,535,168
    short* h1       = qkvbuf;                         // overlays qkv+attn (154,140,672)
    short* wqkvT    = (short*)(ws + 269746176);       // 221,184
    short* wprojT   = (short*)(ws + 269967360);       // 73,728
    short* wfc1T    = (short*)(ws + 270041088);       // 294,912
    short* wfc2T    = (short*)(ws + 270336000);       // 294,912

    // weight converts/transposes
    k_transpose<<<dim3((192 * 576 + 255) / 256), dim3(256), 0, stream>>>(qkv_w, wqkvT, 192, 576);
    k_transpose<<<dim3((192 * 192 + 255) / 256), dim3(256), 0, stream>>>(proj_w, wprojT, 192, 192);
    k_transpose<<<dim3((192 * 768 + 255) / 256), dim3(256), 0, stream>>>(fc1_w, wfc1T, 192, 768);
    k_transpose<<<dim3((768 * 192 + 255) / 256), dim3(256), 0, stream>>>(fc2_w, wfc2T, 768, 192);

    // stage 1: cpe0 + LN1 (windowed bf16 ln out)
    k_cpe_ln<<<dim3(Tt / CPE_TPB), dim3(192), 0, stream>>>(x, cpe0_w, cpe0_b, n1_g, n1_b,
                                                           shortcut, lnbuf, 1);
    // qkv projection -> natural [Tt,576] layout
    k_gemm_qkv<<<dim3(9, Tt / 64), dim3(256), 0, stream>>>(lnbuf, wqkvT, qkv_b, qkvbuf);
    // window attention (per-window blocks, head gather inside)
    k_attn<<<dim3(NWIN), dim3(256), 0, stream>>>(qkvbuf, attnout);
    // output projection + shortcut residual -> y0 (in place over shortcut)
    k_gemm_proj<<<dim3(3, Tt / 64), dim3(256), 0, stream>>>(attnout, wprojT, proj_b, shortcut);
    // stage 2: cpe1 + LN2 (token-major ln out); y -> d_out
    k_cpe_ln<<<dim3(Tt / CPE_TPB), dim3(192), 0, stream>>>(shortcut, cpe1_w, cpe1_b, n2_g, n2_b,
                                                           out, lnbuf, 0);
    // MLP
    k_gemm_fc1<<<dim3(12, Tt / 64), dim3(256), 0, stream>>>(lnbuf, wfc1T, fc1_b, h1);
    k_gemm_fc2<<<dim3(3, Tt / 64), dim3(256), 0, stream>>>(h1, wfc2T, fc2_b, out);
}

// Round 3
// 1496.448 us; speedup vs baseline: 1.3896x; 1.0485x over previous
//
#include <hip/hip_runtime.h>
#include <hip/hip_bf16.h>
#include <math.h>

// Problem constants
#define Bn   32
#define Hh   56
#define Wd   56
#define Cc   192
#define NHh  6
#define HDim 32
#define HIDN 768
#define Tt   (Bn*Hh*Wd)          // 100352 tokens
#define NWIN (Bn*64)             // 2048 windows

typedef __attribute__((ext_vector_type(8))) short short8;
typedef __attribute__((ext_vector_type(4))) float floatx4;

__device__ __forceinline__ short f2bf(float f) {
    unsigned u = __float_as_uint(f);
    u += 0x7fffu + ((u >> 16) & 1u);     // round-to-nearest-even
    return (short)(u >> 16);
}
__device__ __forceinline__ float bf2f(short s) {
    return __uint_as_float(((unsigned)(unsigned short)s) << 16);
}

// ---------------------------------------------------------------------------
// Weight transpose + bf16 convert: W[K,N] fp32 -> WT[N,K] bf16
// ---------------------------------------------------------------------------
__global__ void k_transpose(const float* __restrict__ W, short* __restrict__ WT,
                            int K, int N) {
    int idx = blockIdx.x * 256 + threadIdx.x;
    if (idx >= K * N) return;
    int n = idx / K, k = idx % K;        // coalesced writes
    WT[idx] = f2bf(W[k * N + n]);
}

// ---------------------------------------------------------------------------
// Fused depthwise-3x3 CPE (residual) + LayerNorm. 8 tokens per block.
// ---------------------------------------------------------------------------
#define CPE_TPB 8
__global__ void __launch_bounds__(192) k_cpe_ln(
    const float* __restrict__ xin, const float* __restrict__ wconv,
    const float* __restrict__ bconv, const float* __restrict__ g,
    const float* __restrict__ beta, float* __restrict__ ysum_out,
    short* __restrict__ ln_out, int windowed)
{
    int c = threadIdx.x;
    __shared__ float wl[Cc * 9];
    __shared__ float red[6];
    for (int i = c; i < Cc * 9; i += 192) wl[i] = wconv[i];
    float bcv = bconv[c], gc = g[c], bc = beta[c];
    __syncthreads();

    int t0 = blockIdx.x * CPE_TPB;
    for (int tk = 0; tk < CPE_TPB; ++tk) {
        int blk = t0 + tk;
        int b = blk / (Hh * Wd);
        int rem = blk % (Hh * Wd);
        int h = rem / Wd, w = rem % Wd;

        float s = bcv;
        #pragma unroll
        for (int ky = 0; ky < 3; ++ky) {
            int hy = h + ky - 1;
            if (hy < 0 || hy >= Hh) continue;
            #pragma unroll
            for (int kx = 0; kx < 3; ++kx) {
                int wx = w + kx - 1;
                if (wx < 0 || wx >= Wd) continue;
                s += wl[c * 9 + ky * 3 + kx] *
                     xin[((size_t)b * (Hh * Wd) + hy * Wd + wx) * Cc + c];
            }
        }
        float val = xin[(size_t)blk * Cc + c] + s;
        ysum_out[(size_t)blk * Cc + c] = val;

        float p = val, p2 = val * val;
        #pragma unroll
        for (int off = 32; off; off >>= 1) {
            p  += __shfl_xor(p,  off, 64);
            p2 += __shfl_xor(p2, off, 64);
        }
        int wid = c >> 6;
        if ((c & 63) == 0) { red[wid * 2] = p; red[wid * 2 + 1] = p2; }
        __syncthreads();
        float sum  = red[0] + red[2] + red[4];
        float sum2 = red[1] + red[3] + red[5];
        __syncthreads();
        float mean = sum * (1.0f / Cc);
        float var  = sum2 * (1.0f / Cc) - mean * mean;
        float nrm  = (val - mean) * rsqrtf(var + 1e-5f) * gc + bc;

        int r;
        if (windowed) {
            int win = b * 64 + (h & 7) * 8 + (w & 7);
            int pos = (h >> 3) * 7 + (w >> 3);
            r = win * 49 + pos;
        } else {
            r = blk;
        }
        ln_out[(size_t)r * Cc + c] = f2bf(nrm);
    }
}

// ---------------------------------------------------------------------------
// GEMM helpers: A-fragments cached in registers for whole K; n-tiles looped
// in-wave so A is fetched from HBM exactly once per 64-row block.
// ---------------------------------------------------------------------------
template<int KS>
__device__ __forceinline__ void load_af(const short* __restrict__ A, int K,
                                        int m0, int lane, short8* af) {
    const short* p = A + (size_t)(m0 + (lane & 15)) * K + (lane >> 4) * 8;
    #pragma unroll
    for (int k = 0; k < KS; ++k) af[k] = *(const short8*)(p + k * 32);
}

template<int KS>
__device__ __forceinline__ floatx4 ntile(const short8* af,
                                         const short* __restrict__ BT, int K,
                                         int n0, int lane) {
    floatx4 acc = {0, 0, 0, 0};
    const short* bp = BT + (size_t)(n0 + (lane & 15)) * K + (lane >> 4) * 8;
    #pragma unroll
    for (int k = 0; k < KS; ++k)
        acc = __builtin_amdgcn_mfma_f32_16x16x32_bf16(
            af[k], *(const short8*)(bp + k * 32), acc, 0, 0, 0);
    return acc;
}

// QKV GEMM: [Tt,576] natural layout (+bias), windowed rows
__global__ void __launch_bounds__(256) k_gemm_qkv(
    const short* __restrict__ A, const short* __restrict__ BT,
    const float* __restrict__ bias, short* __restrict__ qkv)
{
    int m0 = blockIdx.x * 64 + (threadIdx.x >> 6) * 16;
    int lane = threadIdx.x & 63;
    int lcol = lane & 15, quad = lane >> 4;
    short8 af[6];
    load_af<6>(A, Cc, m0, lane, af);
    int m0q = m0 + quad * 4;
    for (int ni = 0; ni < 36; ++ni) {
        floatx4 acc = ntile<6>(af, BT, Cc, ni * 16, lane);
        int col = ni * 16 + lcol;
        float bv = bias[col];
        #pragma unroll
        for (int t = 0; t < 4; ++t)
            qkv[(size_t)(m0q + t) * 576 + col] = f2bf(acc[t] + bv);
    }
}

// ---------------------------------------------------------------------------
// MFMA window attention: one wave (64 thr) per (window, head).
// Q/K: [64][40] bf16 LDS (pad 40 keeps b128 frags ~2-way); Vt: [32][72];
// P: [64][72]. Softmax in registers via 16-lane quad shfl_xor.
// ---------------------------------------------------------------------------
__global__ void __launch_bounds__(64) k_attn(
    const short* __restrict__ C, short* __restrict__ aout)
{
    int win = blockIdx.x, h = blockIdx.y;
    int lane = threadIdx.x;
    int lcol = lane & 15, quad = lane >> 4;
    __shared__ __align__(16) short Q[64 * 40];
    __shared__ __align__(16) short Kb[64 * 40];
    __shared__ __align__(16) short Vt[32 * 72];
    __shared__ __align__(16) short P[64 * 72];

    // stage Q,K (p-major rows, zero-pad p>=49)
    #pragma unroll 4
    for (int it = 0; it < 32; ++it) {
        int idx = it * 64 + lane;
        int p = idx >> 5, d = idx & 31;
        bool ok = p < 49;
        size_t ro = ((size_t)win * 49 + (ok ? p : 0)) * 576 + d * 18 + h;
        Q[p * 40 + d]  = ok ? C[ro]     : (short)0;
        Kb[p * 40 + d] = ok ? C[ro + 6] : (short)0;
    }
    // stage Vt (d-major, p consecutive across lanes)
    #pragma unroll 4
    for (int it = 0; it < 32; ++it) {
        int idx = it * 64 + lane;
        int p = idx & 63, d = idx >> 6;
        bool ok = p < 49;
        size_t ro = ((size_t)win * 49 + (ok ? p : 0)) * 576 + d * 18 + 12 + h;
        Vt[d * 72 + p] = ok ? C[ro] : (short)0;
    }
    __syncthreads();

    // S = Q K^T  (16 MFMA accumulators, K-dim=32 in one instruction)
    floatx4 s[4][4];
    #pragma unroll
    for (int mi = 0; mi < 4; ++mi) {
        short8 aq = *(const short8*)(Q + (mi * 16 + lcol) * 40 + quad * 8);
        #pragma unroll
        for (int ni = 0; ni < 4; ++ni) {
            short8 bk = *(const short8*)(Kb + (ni * 16 + lcol) * 40 + quad * 8);
            floatx4 z = {0, 0, 0, 0};
            s[mi][ni] = __builtin_amdgcn_mfma_f32_16x16x32_bf16(aq, bk, z, 0, 0, 0);
        }
    }

    // register softmax: row = mi*16 + quad*4 + reg lives across the 16 lanes
    // of this quad group (cols = ni*16 + lcol)
    const float scale = 0.17677669529663688f;   // 1/sqrt(32)
    #pragma unroll
    for (int mi = 0; mi < 4; ++mi) {
        #pragma unroll
        for (int reg = 0; reg < 4; ++reg) {
            float vv[4];
            float mx = -3e38f;
            #pragma unroll
            for (int ni = 0; ni < 4; ++ni) {
                int col = ni * 16 + lcol;
                float v = (col < 49) ? s[mi][ni][reg] * scale : -3e38f;
                vv[ni] = v;
                mx = fmaxf(mx, v);
            }
            #pragma unroll
            for (int off = 1; off < 16; off <<= 1)
                mx = fmaxf(mx, __shfl_xor(mx, off, 64));
            float sum = 0.f;
            #pragma unroll
            for (int ni = 0; ni < 4; ++ni) {
                int col = ni * 16 + lcol;
                float e = (col < 49) ? __expf(vv[ni] - mx) : 0.f;
                vv[ni] = e;
                sum += e;
            }
            #pragma unroll
            for (int off = 1; off < 16; off <<= 1)
                sum += __shfl_xor(sum, off, 64);
            float inv = 1.0f / sum;
            int row = mi * 16 + quad * 4 + reg;
            #pragma unroll
            for (int ni = 0; ni < 4; ++ni)
                P[row * 72 + ni * 16 + lcol] = f2bf(vv[ni] * inv);
        }
    }
    __syncthreads();

    // O = P V  (K-dim = 64 -> 2 MFMA steps)
    #pragma unroll
    for (int mi = 0; mi < 4; ++mi) {
        short8 a0 = *(const short8*)(P + (mi * 16 + lcol) * 72 + quad * 8);
        short8 a1 = *(const short8*)(P + (mi * 16 + lcol) * 72 + 32 + quad * 8);
        #pragma unroll
        for (int nd = 0; nd < 2; ++nd) {
            short8 b0 = *(const short8*)(Vt + (nd * 16 + lcol) * 72 + quad * 8);
            short8 b1 = *(const short8*)(Vt + (nd * 16 + lcol) * 72 + 32 + quad * 8);
            floatx4 z = {0, 0, 0, 0};
            floatx4 o = __builtin_amdgcn_mfma_f32_16x16x32_bf16(a0, b0, z, 0, 0, 0);
            o = __builtin_amdgcn_mfma_f32_16x16x32_bf16(a1, b1, o, 0, 0, 0);
            #pragma unroll
            for (int reg = 0; reg < 4; ++reg) {
                int row = mi * 16 + quad * 4 + reg;
                if (row < 49)
                    aout[((size_t)win * 49 + row) * Cc + h * HDim + nd * 16 + lcol] =
                        f2bf(o[reg]);
            }
        }
    }
}

// proj GEMM: windowed rows -> token scatter, + bias + shortcut (in place)
__global__ void __launch_bounds__(256) k_gemm_proj(
    const short* __restrict__ A, const short* __restrict__ BT,
    const float* __restrict__ bias, float* __restrict__ y0)
{
    int m0 = blockIdx.x * 64 + (threadIdx.x >> 6) * 16;
    int lane = threadIdx.x & 63;
    int lcol = lane & 15, quad = lane >> 4;
    short8 af[6];
    load_af<6>(A, Cc, m0, lane, af);
    int m0q = m0 + quad * 4;
    for (int ni = 0; ni < 12; ++ni) {
        floatx4 acc = ntile<6>(af, BT, Cc, ni * 16, lane);
        int col = ni * 16 + lcol;
        float bv = bias[col];
        #pragma unroll
        for (int t = 0; t < 4; ++t) {
            int r = m0q + t;
            int win = r / 49, p = r % 49;
            int b = win >> 6, wm = (win >> 3) & 7, wwm = win & 7;
            int hh = (p / 7) * 8 + wm, w = (p % 7) * 8 + wwm;
            size_t ti = ((size_t)b * (Hh * Wd) + hh * Wd + w) * Cc + col;
            y0[ti] += acc[t] + bv;
        }
    }
}

// fc1 GEMM + exact GELU -> h1 bf16 [Tt, 768]
__global__ void __launch_bounds__(256) k_gemm_fc1(
    const short* __restrict__ A, const short* __restrict__ BT,
    const float* __restrict__ bias, short* __restrict__ h1)
{
    int m0 = blockIdx.x * 64 + (threadIdx.x >> 6) * 16;
    int lane = threadIdx.x & 63;
    int lcol = lane & 15, quad = lane >> 4;
    short8 af[6];
    load_af<6>(A, Cc, m0, lane, af);
    int m0q = m0 + quad * 4;
    for (int ni = 0; ni < 48; ++ni) {
        floatx4 acc = ntile<6>(af, BT, Cc, ni * 16, lane);
        int col = ni * 16 + lcol;
        float bv = bias[col];
        #pragma unroll
        for (int t = 0; t < 4; ++t) {
            float v = acc[t] + bv;
            float gl = 0.5f * v * (1.0f + erff(v * 0.70710678118654752f));
            h1[(size_t)(m0q + t) * HIDN + col] = f2bf(gl);
        }
    }
}

// fc2 GEMM (K=768) + bias + residual add into d_out
__global__ void __launch_bounds__(256) k_gemm_fc2(
    const short* __restrict__ A, const short* __restrict__ BT,
    const float* __restrict__ bias, float* __restrict__ out)
{
    int m0 = blockIdx.x * 64 + (threadIdx.x >> 6) * 16;
    int lane = threadIdx.x & 63;
    int lcol = lane & 15, quad = lane >> 4;
    short8 af[24];
    load_af<24>(A, HIDN, m0, lane, af);
    int m0q = m0 + quad * 4;
    for (int ni = 0; ni < 12; ++ni) {
        floatx4 acc = ntile<24>(af, BT, HIDN, ni * 16, lane);
        int col = ni * 16 + lcol;
        float bv = bias[col];
        #pragma unroll
        for (int t = 0; t < 4; ++t)
            out[(size_t)(m0q + t) * Cc + col] += acc[t] + bv;
    }
}

// ---------------------------------------------------------------------------
extern "C" void kernel_launch(void* const* d_in, const int* in_sizes, int n_in,
                              void* d_out, int out_size, void* d_ws, size_t ws_size,
                              hipStream_t stream)
{
    (void)in_sizes; (void)n_in; (void)out_size; (void)ws_size;
    const float* x      = (const float*)d_in[0];
    const float* cpe0_w = (const float*)d_in[3];
    const float* cpe0_b = (const float*)d_in[4];
    const float* cpe1_w = (const float*)d_in[5];
    const float* cpe1_b = (const float*)d_in[6];
    const float* n1_g   = (const float*)d_in[7];
    const float* n1_b   = (const float*)d_in[8];
    const float* qkv_w  = (const float*)d_in[9];
    const float* qkv_b  = (const float*)d_in[10];
    const float* proj_w = (const float*)d_in[11];
    const float* proj_b = (const float*)d_in[12];
    const float* n2_g   = (const float*)d_in[13];
    const float* n2_b   = (const float*)d_in[14];
    const float* fc1_w  = (const float*)d_in[15];
    const float* fc1_b  = (const float*)d_in[16];
    const float* fc2_w  = (const float*)d_in[17];
    const float* fc2_b  = (const float*)d_in[18];
    float* out = (float*)d_out;

    char* ws = (char*)d_ws;
    float* shortcut = (float*)ws;                     // 77,070,336  (fp32 Tt*192)
    short* lnbuf    = (short*)(ws + 77070336);        // 38,535,168  (bf16 Tt*192)
    short* qkvbuf   = (short*)(ws + 115605504);       // 115,605,504 (bf16 Tt*576)
    short* attnout  = (short*)(ws + 231211008);       // 38,535,168
    short* h1       = qkvbuf;                         // overlays qkv+attn
    short* wqkvT    = (short*)(ws + 269746176);       // 221,184
    short* wprojT   = (short*)(ws + 269967360);       // 73,728
    short* wfc1T    = (short*)(ws + 270041088);       // 294,912
    short* wfc2T    = (short*)(ws + 270336000);       // 294,912

    k_transpose<<<dim3((192 * 576 + 255) / 256), dim3(256), 0, stream>>>(qkv_w, wqkvT, 192, 576);
    k_transpose<<<dim3((192 * 192 + 255) / 256), dim3(256), 0, stream>>>(proj_w, wprojT, 192, 192);
    k_transpose<<<dim3((192 * 768 + 255) / 256), dim3(256), 0, stream>>>(fc1_w, wfc1T, 192, 768);
    k_transpose<<<dim3((768 * 192 + 255) / 256), dim3(256), 0, stream>>>(fc2_w, wfc2T, 768, 192);

    k_cpe_ln<<<dim3(Tt / CPE_TPB), dim3(192), 0, stream>>>(x, cpe0_w, cpe0_b, n1_g, n1_b,
                                                           shortcut, lnbuf, 1);
    k_gemm_qkv<<<dim3(Tt / 64), dim3(256), 0, stream>>>(lnbuf, wqkvT, qkv_b, qkvbuf);
    k_attn<<<dim3(NWIN, NHh), dim3(64), 0, stream>>>(qkvbuf, attnout);
    k_gemm_proj<<<dim3(Tt / 64), dim3(256), 0, stream>>>(attnout, wprojT, proj_b, shortcut);
    k_cpe_ln<<<dim3(Tt / CPE_TPB), dim3(192), 0, stream>>>(shortcut, cpe1_w, cpe1_b, n2_g, n2_b,
                                                           out, lnbuf, 0);
    k_gemm_fc1<<<dim3(Tt / 64), dim3(256), 0, stream>>>(lnbuf, wfc1T, fc1_b, h1);
    k_gemm_fc2<<<dim3(Tt / 64), dim3(256), 0, stream>>>(h1, wfc2T, fc2_b, out);
}

// Round 4
// 1054.812 us; speedup vs baseline: 1.9715x; 1.4187x over previous
//
#include <hip/hip_runtime.h>
#include <hip/hip_bf16.h>
#include <math.h>

// Problem constants
#define Bn   32
#define Hh   56
#define Wd   56
#define Cc   192
#define NHh  6
#define HDim 32
#define HIDN 768
#define Tt   (Bn*Hh*Wd)          // 100352 tokens
#define NWIN (Bn*64)             // 2048 windows

typedef __attribute__((ext_vector_type(8))) short short8;
typedef __attribute__((ext_vector_type(4))) float floatx4;

__device__ __forceinline__ short f2bf(float f) {
    unsigned u = __float_as_uint(f);
    u += 0x7fffu + ((u >> 16) & 1u);     // round-to-nearest-even
    return (short)(u >> 16);
}
__device__ __forceinline__ float bf2f(short s) {
    return __uint_as_float(((unsigned)(unsigned short)s) << 16);
}

// ---------------------------------------------------------------------------
// Weight transpose + bf16 convert: W[K,N] fp32 -> WT[N,K] bf16
// ---------------------------------------------------------------------------
__global__ void k_transpose(const float* __restrict__ W, short* __restrict__ WT,
                            int K, int N) {
    int idx = blockIdx.x * 256 + threadIdx.x;
    if (idx >= K * N) return;
    int n = idx / K, k = idx % K;        // coalesced writes
    WT[idx] = f2bf(W[k * N + n]);
}

// ---------------------------------------------------------------------------
// Fused depthwise-3x3 CPE (residual) + LayerNorm. 8 tokens per block.
// ---------------------------------------------------------------------------
#define CPE_TPB 8
__global__ void __launch_bounds__(192) k_cpe_ln(
    const float* __restrict__ xin, const float* __restrict__ wconv,
    const float* __restrict__ bconv, const float* __restrict__ g,
    const float* __restrict__ beta, float* __restrict__ ysum_out,
    short* __restrict__ ln_out, int windowed)
{
    int c = threadIdx.x;
    __shared__ float wl[Cc * 9];
    __shared__ float red[6];
    for (int i = c; i < Cc * 9; i += 192) wl[i] = wconv[i];
    float bcv = bconv[c], gc = g[c], bc = beta[c];
    __syncthreads();

    int t0 = blockIdx.x * CPE_TPB;
    for (int tk = 0; tk < CPE_TPB; ++tk) {
        int blk = t0 + tk;
        int b = blk / (Hh * Wd);
        int rem = blk % (Hh * Wd);
        int h = rem / Wd, w = rem % Wd;

        float s = bcv;
        #pragma unroll
        for (int ky = 0; ky < 3; ++ky) {
            int hy = h + ky - 1;
            if (hy < 0 || hy >= Hh) continue;
            #pragma unroll
            for (int kx = 0; kx < 3; ++kx) {
                int wx = w + kx - 1;
                if (wx < 0 || wx >= Wd) continue;
                s += wl[c * 9 + ky * 3 + kx] *
                     xin[((size_t)b * (Hh * Wd) + hy * Wd + wx) * Cc + c];
            }
        }
        float val = xin[(size_t)blk * Cc + c] + s;
        ysum_out[(size_t)blk * Cc + c] = val;

        float p = val, p2 = val * val;
        #pragma unroll
        for (int off = 32; off; off >>= 1) {
            p  += __shfl_xor(p,  off, 64);
            p2 += __shfl_xor(p2, off, 64);
        }
        int wid = c >> 6;
        if ((c & 63) == 0) { red[wid * 2] = p; red[wid * 2 + 1] = p2; }
        __syncthreads();
        float sum  = red[0] + red[2] + red[4];
        float sum2 = red[1] + red[3] + red[5];
        __syncthreads();
        float mean = sum * (1.0f / Cc);
        float var  = sum2 * (1.0f / Cc) - mean * mean;
        float nrm  = (val - mean) * rsqrtf(var + 1e-5f) * gc + bc;

        int r;
        if (windowed) {
            int win = b * 64 + (h & 7) * 8 + (w & 7);
            int pos = (h >> 3) * 7 + (w >> 3);
            r = win * 49 + pos;
        } else {
            r = blk;
        }
        ln_out[(size_t)r * Cc + c] = f2bf(nrm);
    }
}

// ---------------------------------------------------------------------------
// Tiled MFMA GEMM (m93-style): BM=128, BN=64, BK=32, 256 thr / 4 waves.
// A[M,K] bf16 row-major, BT[N,K] bf16. Wave computes 32 rows x 64 cols.
// EPI: 0=qkv store bf16 ldc=576; 1=proj scatter+=fp32; 2=gelu bf16 ldc=768;
//      3=fp32 += ldc=192.
// ---------------------------------------------------------------------------
template<int K, int EPI>
__global__ void __launch_bounds__(256) k_gemm_tiled(
    const short* __restrict__ A, const short* __restrict__ BT,
    const float* __restrict__ bias, void* __restrict__ outp)
{
    __shared__ __align__(16) short As[128 * 32];
    __shared__ __align__(16) short Bs[64 * 32];
    const int tid = threadIdx.x;
    const int n0 = blockIdx.x * 64;
    const int m0 = blockIdx.y * 128;
    const int w = tid >> 6, lane = tid & 63;
    const int lcol = lane & 15, quad = lane >> 4;

    floatx4 acc[2][4];
    #pragma unroll
    for (int mi = 0; mi < 2; ++mi)
        #pragma unroll
        for (int ni = 0; ni < 4; ++ni) acc[mi][ni] = (floatx4){0, 0, 0, 0};

    // staging coords: 16 B per thread per tile-round; LDS writes fully linear
    const int ar = tid >> 2, ac = (tid & 3) * 8;
    const short* agp  = A + (size_t)(m0 + ar) * K + ac;
    const short* agp2 = A + (size_t)(m0 + 64 + ar) * K + ac;
    const short* bgp  = BT + (size_t)(n0 + ar) * K + ac;
    short* asw = As + tid * 8;
    short* bsw = Bs + tid * 8;

    const short* ard0 = As + (w * 32 + lcol) * 32 + quad * 8;
    const short* ard1 = As + (w * 32 + 16 + lcol) * 32 + quad * 8;
    const short* brd  = Bs + lcol * 32 + quad * 8;

    for (int k0 = 0; k0 < K; k0 += 32) {
        __syncthreads();
        short8 va0 = *(const short8*)(agp + k0);
        short8 va1 = *(const short8*)(agp2 + k0);
        short8 vb  = *(const short8*)(bgp + k0);
        *(short8*)asw             = va0;
        *(short8*)(asw + 64 * 32) = va1;
        *(short8*)bsw             = vb;
        __syncthreads();
        short8 a0 = *(const short8*)ard0;
        short8 a1 = *(const short8*)ard1;
        #pragma unroll
        for (int ni = 0; ni < 4; ++ni) {
            short8 b = *(const short8*)(brd + ni * 16 * 32);
            acc[0][ni] = __builtin_amdgcn_mfma_f32_16x16x32_bf16(a0, b, acc[0][ni], 0, 0, 0);
            acc[1][ni] = __builtin_amdgcn_mfma_f32_16x16x32_bf16(a1, b, acc[1][ni], 0, 0, 0);
        }
    }

    #pragma unroll
    for (int mi = 0; mi < 2; ++mi) {
        #pragma unroll
        for (int ni = 0; ni < 4; ++ni) {
            int col = n0 + ni * 16 + lcol;
            float bv = bias[col];
            #pragma unroll
            for (int t = 0; t < 4; ++t) {
                int row = m0 + w * 32 + mi * 16 + quad * 4 + t;
                float v = acc[mi][ni][t] + bv;
                if (EPI == 0) {
                    ((short*)outp)[(size_t)row * 576 + col] = f2bf(v);
                } else if (EPI == 1) {
                    int win = row / 49, p = row % 49;
                    int b = win >> 6, wm = (win >> 3) & 7, wwm = win & 7;
                    int hh = (p / 7) * 8 + wm, ww = (p % 7) * 8 + wwm;
                    ((float*)outp)[((size_t)b * (Hh * Wd) + hh * Wd + ww) * Cc + col] += v;
                } else if (EPI == 2) {
                    float gl = 0.5f * v * (1.0f + erff(v * 0.70710678118654752f));
                    ((short*)outp)[(size_t)row * HIDN + col] = f2bf(gl);
                } else {
                    ((float*)outp)[(size_t)row * Cc + col] += v;
                }
            }
        }
    }
}

// ---------------------------------------------------------------------------
// MFMA window attention: one wave (64 thr) per (window, head).
// ---------------------------------------------------------------------------
__global__ void __launch_bounds__(64) k_attn(
    const short* __restrict__ C, short* __restrict__ aout)
{
    int win = blockIdx.x, h = blockIdx.y;
    int lane = threadIdx.x;
    int lcol = lane & 15, quad = lane >> 4;
    __shared__ __align__(16) short Q[64 * 40];
    __shared__ __align__(16) short Kb[64 * 40];
    __shared__ __align__(16) short Vt[32 * 72];
    __shared__ __align__(16) short P[64 * 72];

    #pragma unroll 4
    for (int it = 0; it < 32; ++it) {
        int idx = it * 64 + lane;
        int p = idx >> 5, d = idx & 31;
        bool ok = p < 49;
        size_t ro = ((size_t)win * 49 + (ok ? p : 0)) * 576 + d * 18 + h;
        Q[p * 40 + d]  = ok ? C[ro]     : (short)0;
        Kb[p * 40 + d] = ok ? C[ro + 6] : (short)0;
    }
    #pragma unroll 4
    for (int it = 0; it < 32; ++it) {
        int idx = it * 64 + lane;
        int p = idx & 63, d = idx >> 6;
        bool ok = p < 49;
        size_t ro = ((size_t)win * 49 + (ok ? p : 0)) * 576 + d * 18 + 12 + h;
        Vt[d * 72 + p] = ok ? C[ro] : (short)0;
    }
    __syncthreads();

    floatx4 s[4][4];
    #pragma unroll
    for (int mi = 0; mi < 4; ++mi) {
        short8 aq = *(const short8*)(Q + (mi * 16 + lcol) * 40 + quad * 8);
        #pragma unroll
        for (int ni = 0; ni < 4; ++ni) {
            short8 bk = *(const short8*)(Kb + (ni * 16 + lcol) * 40 + quad * 8);
            floatx4 z = {0, 0, 0, 0};
            s[mi][ni] = __builtin_amdgcn_mfma_f32_16x16x32_bf16(aq, bk, z, 0, 0, 0);
        }
    }

    const float scale = 0.17677669529663688f;   // 1/sqrt(32)
    #pragma unroll
    for (int mi = 0; mi < 4; ++mi) {
        #pragma unroll
        for (int reg = 0; reg < 4; ++reg) {
            float vv[4];
            float mx = -3e38f;
            #pragma unroll
            for (int ni = 0; ni < 4; ++ni) {
                int col = ni * 16 + lcol;
                float v = (col < 49) ? s[mi][ni][reg] * scale : -3e38f;
                vv[ni] = v;
                mx = fmaxf(mx, v);
            }
            #pragma unroll
            for (int off = 1; off < 16; off <<= 1)
                mx = fmaxf(mx, __shfl_xor(mx, off, 64));
            float sum = 0.f;
            #pragma unroll
            for (int ni = 0; ni < 4; ++ni) {
                int col = ni * 16 + lcol;
                float e = (col < 49) ? __expf(vv[ni] - mx) : 0.f;
                vv[ni] = e;
                sum += e;
            }
            #pragma unroll
            for (int off = 1; off < 16; off <<= 1)
                sum += __shfl_xor(sum, off, 64);
            float inv = 1.0f / sum;
            int row = mi * 16 + quad * 4 + reg;
            #pragma unroll
            for (int ni = 0; ni < 4; ++ni)
                P[row * 72 + ni * 16 + lcol] = f2bf(vv[ni] * inv);
        }
    }
    __syncthreads();

    #pragma unroll
    for (int mi = 0; mi < 4; ++mi) {
        short8 a0 = *(const short8*)(P + (mi * 16 + lcol) * 72 + quad * 8);
        short8 a1 = *(const short8*)(P + (mi * 16 + lcol) * 72 + 32 + quad * 8);
        #pragma unroll
        for (int nd = 0; nd < 2; ++nd) {
            short8 b0 = *(const short8*)(Vt + (nd * 16 + lcol) * 72 + quad * 8);
            short8 b1 = *(const short8*)(Vt + (nd * 16 + lcol) * 72 + 32 + quad * 8);
            floatx4 z = {0, 0, 0, 0};
            floatx4 o = __builtin_amdgcn_mfma_f32_16x16x32_bf16(a0, b0, z, 0, 0, 0);
            o = __builtin_amdgcn_mfma_f32_16x16x32_bf16(a1, b1, o, 0, 0, 0);
            #pragma unroll
            for (int reg = 0; reg < 4; ++reg) {
                int row = mi * 16 + quad * 4 + reg;
                if (row < 49)
                    aout[((size_t)win * 49 + row) * Cc + h * HDim + nd * 16 + lcol] =
                        f2bf(o[reg]);
            }
        }
    }
}

// ---------------------------------------------------------------------------
extern "C" void kernel_launch(void* const* d_in, const int* in_sizes, int n_in,
                              void* d_out, int out_size, void* d_ws, size_t ws_size,
                              hipStream_t stream)
{
    (void)in_sizes; (void)n_in; (void)out_size; (void)ws_size;
    const float* x      = (const float*)d_in[0];
    const float* cpe0_w = (const float*)d_in[3];
    const float* cpe0_b = (const float*)d_in[4];
    const float* cpe1_w = (const float*)d_in[5];
    const float* cpe1_b = (const float*)d_in[6];
    const float* n1_g   = (const float*)d_in[7];
    const float* n1_b   = (const float*)d_in[8];
    const float* qkv_w  = (const float*)d_in[9];
    const float* qkv_b  = (const float*)d_in[10];
    const float* proj_w = (const float*)d_in[11];
    const float* proj_b = (const float*)d_in[12];
    const float* n2_g   = (const float*)d_in[13];
    const float* n2_b   = (const float*)d_in[14];
    const float* fc1_w  = (const float*)d_in[15];
    const float* fc1_b  = (const float*)d_in[16];
    const float* fc2_w  = (const float*)d_in[17];
    const float* fc2_b  = (const float*)d_in[18];
    float* out = (float*)d_out;

    char* ws = (char*)d_ws;
    float* shortcut = (float*)ws;                     // 77,070,336  (fp32 Tt*192)
    short* lnbuf    = (short*)(ws + 77070336);        // 38,535,168  (bf16 Tt*192)
    short* qkvbuf   = (short*)(ws + 115605504);       // 115,605,504 (bf16 Tt*576)
    short* attnout  = (short*)(ws + 231211008);       // 38,535,168
    short* h1       = qkvbuf;                         // overlays qkv+attn
    short* wqkvT    = (short*)(ws + 269746176);       // 221,184
    short* wprojT   = (short*)(ws + 269967360);       // 73,728
    short* wfc1T    = (short*)(ws + 270041088);       // 294,912
    short* wfc2T    = (short*)(ws + 270336000);       // 294,912

    k_transpose<<<dim3((192 * 576 + 255) / 256), dim3(256), 0, stream>>>(qkv_w, wqkvT, 192, 576);
    k_transpose<<<dim3((192 * 192 + 255) / 256), dim3(256), 0, stream>>>(proj_w, wprojT, 192, 192);
    k_transpose<<<dim3((192 * 768 + 255) / 256), dim3(256), 0, stream>>>(fc1_w, wfc1T, 192, 768);
    k_transpose<<<dim3((768 * 192 + 255) / 256), dim3(256), 0, stream>>>(fc2_w, wfc2T, 768, 192);

    k_cpe_ln<<<dim3(Tt / CPE_TPB), dim3(192), 0, stream>>>(x, cpe0_w, cpe0_b, n1_g, n1_b,
                                                           shortcut, lnbuf, 1);
    k_gemm_tiled<192, 0><<<dim3(9, Tt / 128), dim3(256), 0, stream>>>(lnbuf, wqkvT, qkv_b, qkvbuf);
    k_attn<<<dim3(NWIN, NHh), dim3(64), 0, stream>>>(qkvbuf, attnout);
    k_gemm_tiled<192, 1><<<dim3(3, Tt / 128), dim3(256), 0, stream>>>(attnout, wprojT, proj_b, shortcut);
    k_cpe_ln<<<dim3(Tt / CPE_TPB), dim3(192), 0, stream>>>(shortcut, cpe1_w, cpe1_b, n2_g, n2_b,
                                                           out, lnbuf, 0);
    k_gemm_tiled<192, 2><<<dim3(12, Tt / 128), dim3(256), 0, stream>>>(lnbuf, wfc1T, fc1_b, h1);
    k_gemm_tiled<768, 3><<<dim3(3, Tt / 128), dim3(256), 0, stream>>>(h1, wfc2T, fc2_b, out);
}

// Round 5
// 1029.514 us; speedup vs baseline: 2.0199x; 1.0246x over previous
//
#include <hip/hip_runtime.h>
#include <hip/hip_bf16.h>
#include <math.h>

// Problem constants
#define Bn   32
#define Hh   56
#define Wd   56
#define Cc   192
#define NHh  6
#define HDim 32
#define HIDN 768
#define Tt   (Bn*Hh*Wd)          // 100352 tokens
#define NWIN (Bn*64)             // 2048 windows

typedef __attribute__((ext_vector_type(8))) short short8;
typedef __attribute__((ext_vector_type(4))) float floatx4;

__device__ __forceinline__ short f2bf(float f) {
    unsigned u = __float_as_uint(f);
    u += 0x7fffu + ((u >> 16) & 1u);     // round-to-nearest-even
    return (short)(u >> 16);
}
__device__ __forceinline__ float bf2f(short s) {
    return __uint_as_float(((unsigned)(unsigned short)s) << 16);
}

// ---------------------------------------------------------------------------
// Weight transpose + bf16 convert: W[K,N] fp32 -> WT[N,K] bf16
// ---------------------------------------------------------------------------
__global__ void k_transpose(const float* __restrict__ W, short* __restrict__ WT,
                            int K, int N) {
    int idx = blockIdx.x * 256 + threadIdx.x;
    if (idx >= K * N) return;
    int n = idx / K, k = idx % K;        // coalesced writes
    WT[idx] = f2bf(W[k * N + n]);
}

// ---------------------------------------------------------------------------
// Fused depthwise-3x3 CPE (residual) + LayerNorm. 8 tokens per block.
// ---------------------------------------------------------------------------
#define CPE_TPB 8
__global__ void __launch_bounds__(192) k_cpe_ln(
    const float* __restrict__ xin, const float* __restrict__ wconv,
    const float* __restrict__ bconv, const float* __restrict__ g,
    const float* __restrict__ beta, float* __restrict__ ysum_out,
    short* __restrict__ ln_out, int windowed)
{
    int c = threadIdx.x;
    __shared__ float wl[Cc * 9];
    __shared__ float red[6];
    for (int i = c; i < Cc * 9; i += 192) wl[i] = wconv[i];
    float bcv = bconv[c], gc = g[c], bc = beta[c];
    __syncthreads();

    int t0 = blockIdx.x * CPE_TPB;
    for (int tk = 0; tk < CPE_TPB; ++tk) {
        int blk = t0 + tk;
        int b = blk / (Hh * Wd);
        int rem = blk % (Hh * Wd);
        int h = rem / Wd, w = rem % Wd;

        float s = bcv;
        #pragma unroll
        for (int ky = 0; ky < 3; ++ky) {
            int hy = h + ky - 1;
            if (hy < 0 || hy >= Hh) continue;
            #pragma unroll
            for (int kx = 0; kx < 3; ++kx) {
                int wx = w + kx - 1;
                if (wx < 0 || wx >= Wd) continue;
                s += wl[c * 9 + ky * 3 + kx] *
                     xin[((size_t)b * (Hh * Wd) + hy * Wd + wx) * Cc + c];
            }
        }
        float val = xin[(size_t)blk * Cc + c] + s;
        ysum_out[(size_t)blk * Cc + c] = val;

        float p = val, p2 = val * val;
        #pragma unroll
        for (int off = 32; off; off >>= 1) {
            p  += __shfl_xor(p,  off, 64);
            p2 += __shfl_xor(p2, off, 64);
        }
        int wid = c >> 6;
        if ((c & 63) == 0) { red[wid * 2] = p; red[wid * 2 + 1] = p2; }
        __syncthreads();
        float sum  = red[0] + red[2] + red[4];
        float sum2 = red[1] + red[3] + red[5];
        __syncthreads();
        float mean = sum * (1.0f / Cc);
        float var  = sum2 * (1.0f / Cc) - mean * mean;
        float nrm  = (val - mean) * rsqrtf(var + 1e-5f) * gc + bc;

        int r;
        if (windowed) {
            int win = b * 64 + (h & 7) * 8 + (w & 7);
            int pos = (h >> 3) * 7 + (w >> 3);
            r = win * 49 + pos;
        } else {
            r = blk;
        }
        ln_out[(size_t)r * Cc + c] = f2bf(nrm);
    }
}

// ---------------------------------------------------------------------------
// Tiled MFMA GEMM (m93-style): BM=128, BN=64, BK=32, 256 thr / 4 waves.
// ---------------------------------------------------------------------------
template<int K, int EPI>
__global__ void __launch_bounds__(256) k_gemm_tiled(
    const short* __restrict__ A, const short* __restrict__ BT,
    const float* __restrict__ bias, void* __restrict__ outp)
{
    __shared__ __align__(16) short As[128 * 32];
    __shared__ __align__(16) short Bs[64 * 32];
    const int tid = threadIdx.x;
    const int n0 = blockIdx.x * 64;
    const int m0 = blockIdx.y * 128;
    const int w = tid >> 6, lane = tid & 63;
    const int lcol = lane & 15, quad = lane >> 4;

    floatx4 acc[2][4];
    #pragma unroll
    for (int mi = 0; mi < 2; ++mi)
        #pragma unroll
        for (int ni = 0; ni < 4; ++ni) acc[mi][ni] = (floatx4){0, 0, 0, 0};

    const int ar = tid >> 2, ac = (tid & 3) * 8;
    const short* agp  = A + (size_t)(m0 + ar) * K + ac;
    const short* agp2 = A + (size_t)(m0 + 64 + ar) * K + ac;
    const short* bgp  = BT + (size_t)(n0 + ar) * K + ac;
    short* asw = As + tid * 8;
    short* bsw = Bs + tid * 8;

    const short* ard0 = As + (w * 32 + lcol) * 32 + quad * 8;
    const short* ard1 = As + (w * 32 + 16 + lcol) * 32 + quad * 8;
    const short* brd  = Bs + lcol * 32 + quad * 8;

    for (int k0 = 0; k0 < K; k0 += 32) {
        __syncthreads();
        short8 va0 = *(const short8*)(agp + k0);
        short8 va1 = *(const short8*)(agp2 + k0);
        short8 vb  = *(const short8*)(bgp + k0);
        *(short8*)asw             = va0;
        *(short8*)(asw + 64 * 32) = va1;
        *(short8*)bsw             = vb;
        __syncthreads();
        short8 a0 = *(const short8*)ard0;
        short8 a1 = *(const short8*)ard1;
        #pragma unroll
        for (int ni = 0; ni < 4; ++ni) {
            short8 b = *(const short8*)(brd + ni * 16 * 32);
            acc[0][ni] = __builtin_amdgcn_mfma_f32_16x16x32_bf16(a0, b, acc[0][ni], 0, 0, 0);
            acc[1][ni] = __builtin_amdgcn_mfma_f32_16x16x32_bf16(a1, b, acc[1][ni], 0, 0, 0);
        }
    }

    #pragma unroll
    for (int mi = 0; mi < 2; ++mi) {
        #pragma unroll
        for (int ni = 0; ni < 4; ++ni) {
            int col = n0 + ni * 16 + lcol;
            float bv = bias[col];
            #pragma unroll
            for (int t = 0; t < 4; ++t) {
                int row = m0 + w * 32 + mi * 16 + quad * 4 + t;
                float v = acc[mi][ni][t] + bv;
                if (EPI == 0) {
                    ((short*)outp)[(size_t)row * 576 + col] = f2bf(v);
                } else if (EPI == 1) {
                    int win = row / 49, p = row % 49;
                    int b = win >> 6, wm = (win >> 3) & 7, wwm = win & 7;
                    int hh = (p / 7) * 8 + wm, ww = (p % 7) * 8 + wwm;
                    ((float*)outp)[((size_t)b * (Hh * Wd) + hh * Wd + ww) * Cc + col] += v;
                } else if (EPI == 2) {
                    float gl = 0.5f * v * (1.0f + erff(v * 0.70710678118654752f));
                    ((short*)outp)[(size_t)row * HIDN + col] = f2bf(gl);
                } else {
                    ((float*)outp)[(size_t)row * Cc + col] += v;
                }
            }
        }
    }
}

// ---------------------------------------------------------------------------
// MFMA window attention: one wave (64 thr) per (window, head).
// Head on fast grid axis so same-window blocks are dispatch-adjacent (L2/L3
// tile reuse). LDS overlay: P reuses the dead Q/K region (wave-local LDS is
// in-order; no barrier needed). 14,848 B/block -> ~10 blocks/CU.
// ---------------------------------------------------------------------------
__global__ void __launch_bounds__(64) k_attn(
    const short* __restrict__ C, short* __restrict__ aout)
{
    int h = blockIdx.x, win = blockIdx.y;
    int lane = threadIdx.x;
    int lcol = lane & 15, quad = lane >> 4;
    __shared__ __align__(16) short buf[7424];
    short* Q  = buf;            // [64*40]
    short* Kb = buf + 2560;     // [64*40]
    short* Vt = buf + 5120;     // [32*72]
    short* P  = buf;            // [64*72] overlays Q+Kb after S-phase

    #pragma unroll 4
    for (int it = 0; it < 32; ++it) {
        int idx = it * 64 + lane;
        int p = idx >> 5, d = idx & 31;
        bool ok = p < 49;
        size_t ro = ((size_t)win * 49 + (ok ? p : 0)) * 576 + d * 18 + h;
        Q[p * 40 + d]  = ok ? C[ro]     : (short)0;
        Kb[p * 40 + d] = ok ? C[ro + 6] : (short)0;
    }
    #pragma unroll 4
    for (int it = 0; it < 32; ++it) {
        int idx = it * 64 + lane;
        int p = idx & 63, d = idx >> 6;
        bool ok = p < 49;
        size_t ro = ((size_t)win * 49 + (ok ? p : 0)) * 576 + d * 18 + 12 + h;
        Vt[d * 72 + p] = ok ? C[ro] : (short)0;
    }

    floatx4 s[4][4];
    #pragma unroll
    for (int mi = 0; mi < 4; ++mi) {
        short8 aq = *(const short8*)(Q + (mi * 16 + lcol) * 40 + quad * 8);
        #pragma unroll
        for (int ni = 0; ni < 4; ++ni) {
            short8 bk = *(const short8*)(Kb + (ni * 16 + lcol) * 40 + quad * 8);
            floatx4 z = {0, 0, 0, 0};
            s[mi][ni] = __builtin_amdgcn_mfma_f32_16x16x32_bf16(aq, bk, z, 0, 0, 0);
        }
    }

    const float scale = 0.17677669529663688f;   // 1/sqrt(32)
    #pragma unroll
    for (int mi = 0; mi < 4; ++mi) {
        #pragma unroll
        for (int reg = 0; reg < 4; ++reg) {
            float vv[4];
            float mx = -3e38f;
            #pragma unroll
            for (int ni = 0; ni < 4; ++ni) {
                int col = ni * 16 + lcol;
                float v = (col < 49) ? s[mi][ni][reg] * scale : -3e38f;
                vv[ni] = v;
                mx = fmaxf(mx, v);
            }
            #pragma unroll
            for (int off = 1; off < 16; off <<= 1)
                mx = fmaxf(mx, __shfl_xor(mx, off, 64));
            float sum = 0.f;
            #pragma unroll
            for (int ni = 0; ni < 4; ++ni) {
                int col = ni * 16 + lcol;
                float e = (col < 49) ? __expf(vv[ni] - mx) : 0.f;
                vv[ni] = e;
                sum += e;
            }
            #pragma unroll
            for (int off = 1; off < 16; off <<= 1)
                sum += __shfl_xor(sum, off, 64);
            float inv = 1.0f / sum;
            int row = mi * 16 + quad * 4 + reg;
            #pragma unroll
            for (int ni = 0; ni < 4; ++ni)
                P[row * 72 + ni * 16 + lcol] = f2bf(vv[ni] * inv);
        }
    }

    #pragma unroll
    for (int mi = 0; mi < 4; ++mi) {
        short8 a0 = *(const short8*)(P + (mi * 16 + lcol) * 72 + quad * 8);
        short8 a1 = *(const short8*)(P + (mi * 16 + lcol) * 72 + 32 + quad * 8);
        #pragma unroll
        for (int nd = 0; nd < 2; ++nd) {
            short8 b0 = *(const short8*)(Vt + (nd * 16 + lcol) * 72 + quad * 8);
            short8 b1 = *(const short8*)(Vt + (nd * 16 + lcol) * 72 + 32 + quad * 8);
            floatx4 z = {0, 0, 0, 0};
            floatx4 o = __builtin_amdgcn_mfma_f32_16x16x32_bf16(a0, b0, z, 0, 0, 0);
            o = __builtin_amdgcn_mfma_f32_16x16x32_bf16(a1, b1, o, 0, 0, 0);
            #pragma unroll
            for (int reg = 0; reg < 4; ++reg) {
                int row = mi * 16 + quad * 4 + reg;
                if (row < 49)
                    aout[((size_t)win * 49 + row) * Cc + h * HDim + nd * 16 + lcol] =
                        f2bf(o[reg]);
            }
        }
    }
}

// ---------------------------------------------------------------------------
extern "C" void kernel_launch(void* const* d_in, const int* in_sizes, int n_in,
                              void* d_out, int out_size, void* d_ws, size_t ws_size,
                              hipStream_t stream)
{
    (void)in_sizes; (void)n_in; (void)out_size; (void)ws_size;
    const float* x      = (const float*)d_in[0];
    const float* cpe0_w = (const float*)d_in[3];
    const float* cpe0_b = (const float*)d_in[4];
    const float* cpe1_w = (const float*)d_in[5];
    const float* cpe1_b = (const float*)d_in[6];
    const float* n1_g   = (const float*)d_in[7];
    const float* n1_b   = (const float*)d_in[8];
    const float* qkv_w  = (const float*)d_in[9];
    const float* qkv_b  = (const float*)d_in[10];
    const float* proj_w = (const float*)d_in[11];
    const float* proj_b = (const float*)d_in[12];
    const float* n2_g   = (const float*)d_in[13];
    const float* n2_b   = (const float*)d_in[14];
    const float* fc1_w  = (const float*)d_in[15];
    const float* fc1_b  = (const float*)d_in[16];
    const float* fc2_w  = (const float*)d_in[17];
    const float* fc2_b  = (const float*)d_in[18];
    float* out = (float*)d_out;

    char* ws = (char*)d_ws;
    float* shortcut = (float*)ws;                     // 77,070,336  (fp32 Tt*192)
    short* lnbuf    = (short*)(ws + 77070336);        // 38,535,168  (bf16 Tt*192)
    short* qkvbuf   = (short*)(ws + 115605504);       // 115,605,504 (bf16 Tt*576)
    short* attnout  = (short*)(ws + 231211008);       // 38,535,168
    short* h1       = qkvbuf;                         // overlays qkv+attn
    short* wqkvT    = (short*)(ws + 269746176);       // 221,184
    short* wprojT   = (short*)(ws + 269967360);       // 73,728
    short* wfc1T    = (short*)(ws + 270041088);       // 294,912
    short* wfc2T    = (short*)(ws + 270336000);       // 294,912

    k_transpose<<<dim3((192 * 576 + 255) / 256), dim3(256), 0, stream>>>(qkv_w, wqkvT, 192, 576);
    k_transpose<<<dim3((192 * 192 + 255) / 256), dim3(256), 0, stream>>>(proj_w, wprojT, 192, 192);
    k_transpose<<<dim3((192 * 768 + 255) / 256), dim3(256), 0, stream>>>(fc1_w, wfc1T, 192, 768);
    k_transpose<<<dim3((768 * 192 + 255) / 256), dim3(256), 0, stream>>>(fc2_w, wfc2T, 768, 192);

    k_cpe_ln<<<dim3(Tt / CPE_TPB), dim3(192), 0, stream>>>(x, cpe0_w, cpe0_b, n1_g, n1_b,
                                                           shortcut, lnbuf, 1);
    k_gemm_tiled<192, 0><<<dim3(9, Tt / 128), dim3(256), 0, stream>>>(lnbuf, wqkvT, qkv_b, qkvbuf);
    k_attn<<<dim3(NHh, NWIN), dim3(64), 0, stream>>>(qkvbuf, attnout);
    k_gemm_tiled<192, 1><<<dim3(3, Tt / 128), dim3(256), 0, stream>>>(attnout, wprojT, proj_b, shortcut);
    k_cpe_ln<<<dim3(Tt / CPE_TPB), dim3(192), 0, stream>>>(shortcut, cpe1_w, cpe1_b, n2_g, n2_b,
                                                           out, lnbuf, 0);
    k_gemm_tiled<192, 2><<<dim3(12, Tt / 128), dim3(256), 0, stream>>>(lnbuf, wfc1T, fc1_b, h1);
    k_gemm_tiled<768, 3><<<dim3(3, Tt / 128), dim3(256), 0, stream>>>(h1, wfc2T, fc2_b, out);
}